// Round 1
// baseline (142.300 us; speedup 1.0000x reference)
//
#include <hip/hip_runtime.h>
#include <hip/hip_bf16.h>

#define NND 51
#define FIN 4
#define PDIM 137
#define EMB 32
#define EE 408
#define BD 32
#define PC 5
#define NCH 28            // ceil(137/5)
#define NE (NND*EMB)      // 1632

// ws layout: only the partial-h slabs, [b][chunk][n*EMB+e]
// size = 32*28*1632 floats = 5.85 MB (ws allocation is 256 MiB per the
// harness poison fill, so this fits with huge margin).
#define WS_SLAB 0

// grid(NCH, BD), 256 threads. Fully fused: each block redundantly builds
// Ahat + folded gate mats + softmax in LDS (cheap: ~800 LDS atomics +
// 4x32x32 fold), then stage x -> agg -> gates, and writes its DISJOINT
// partial-h slab (no global atomics, no pre-zeroed workspace needed).
__global__ __launch_bounds__(256) void main_kernel(
    const float* __restrict__ x, const int* __restrict__ ei,
    const float* __restrict__ att,
    const float* __restrict__ Wz, const float* __restrict__ bz,
    const float* __restrict__ Wh, const float* __restrict__ bh,
    const float* __restrict__ Uz, const float* __restrict__ bz2,
    const float* __restrict__ Uh, const float* __restrict__ bh2,
    float* __restrict__ slab)
{
    __shared__ __align__(16) float Am[2604];          // Ahat [d][s] stride 51
    __shared__ __align__(16) float xs[PC * NND * FIN]; // x[pp][n][f], f contig
    __shared__ __align__(16) float ag[PC * NND * FIN]; // agg[pp][d][f]
    __shared__ float Us[2][EMB * EMB];
    __shared__ float Ws2[2][FIN * EMB];
    __shared__ float wu[2 * FIN * EMB];   // folded W*U, [g][f][e]
    __shared__ float beff[64];            // folded b*U + b2, [g][e]
    __shared__ float deg[NND], dinv[NND];
    __shared__ float atts[PDIM], pr[PC];
    __shared__ float smax, sinv;
    __shared__ int   eis[2 * EE];

    int t = threadIdx.x;
    int b = blockIdx.y;
    int c = blockIdx.x;
    int p0 = c * PC;
    int npp = min(PC, PDIM - p0);

    // ---- phase 0: zero + stage everything independent ----
    for (int i = t; i < 2604; i += 256) Am[i] = 0.0f;
    if (t < NND) deg[t] = 0.0f;
    for (int i = t; i < 2 * EE; i += 256) eis[i] = ei[i];
    for (int i = t; i < EMB * EMB; i += 256) { Us[0][i] = Uz[i]; Us[1][i] = Uh[i]; }
    if (t < FIN * EMB) { Ws2[0][t] = Wz[t]; Ws2[1][t] = Wh[t]; }
    if (t < PDIM) atts[t] = att[t];
    if (t < NND * FIN) {
        int n = t >> 2, f = t & 3;
        const float* xp = &x[((b * NND + n) * FIN + f) * PDIM + p0];
        for (int pp = 0; pp < npp; pp++) xs[(pp * NND + n) * 4 + f] = xp[pp];
    }
    __syncthreads();

    // ---- phase 1: degree atomics; wave 3 computes softmax max ----
    for (int e = t; e < EE; e += 256) atomicAdd(&deg[eis[EE + e]], 1.0f);
    if (t >= 192) {
        float m = -1e30f;
        for (int p = t - 192; p < PDIM; p += 64) m = fmaxf(m, atts[p]);
        #pragma unroll
        for (int off = 32; off > 0; off >>= 1) m = fmaxf(m, __shfl_down(m, off));
        if (t == 192) smax = m;
    }
    __syncthreads();

    // ---- phase 2: dinv; exp(att - max) ----
    if (t < NND) dinv[t] = rsqrtf(deg[t] + 1.0f);       // +1 self loop
    if (t >= 64 && t < 64 + PDIM) atts[t - 64] = __expf(atts[t - 64] - smax);
    __syncthreads();

    // ---- phase 3: Ahat atomics; folded mats; exp-sum ----
    for (int e = t; e < EE; e += 256) {
        int s = eis[e], d = eis[EE + e];
        atomicAdd(&Am[d * NND + s], dinv[s] * dinv[d]);
    }
    {   // wu[g][f][e]: t encodes (g,f,e)
        int g = t >> 7, f = (t >> 5) & 3, e2 = t & 31;
        float a = 0.0f;
        #pragma unroll
        for (int k = 0; k < EMB; k++) a += Ws2[g][f * EMB + k] * Us[g][k * EMB + e2];
        wu[t] = a;
    }
    if (t < 64) {
        int g = t >> 5, e2 = t & 31;
        const float* bb = g ? bh : bz;
        const float* b2 = g ? bh2 : bz2;
        float a = b2[e2];
        #pragma unroll
        for (int k = 0; k < EMB; k++) a += bb[k] * Us[g][k * EMB + e2];
        beff[t] = a;
    }
    if (t >= 192) {
        float s = 0.0f;
        for (int p = t - 192; p < PDIM; p += 64) s += atts[p];
        #pragma unroll
        for (int off = 32; off > 0; off >>= 1) s += __shfl_down(s, off);
        if (t == 192) sinv = 1.0f / s;
    }
    __syncthreads();

    // ---- phase 4: diagonal self-loop; probs for this chunk ----
    if (t < NND) Am[t * 52] += dinv[t] * dinv[t];       // t*51 + t
    if (t < npp) pr[t] = atts[p0 + t] * sinv;
    __syncthreads();

    // ---- agg: thread (pp,d) computes agg[pp][d][0..3] ----
    // A scalar reads stride 51 mod 32 banks = <=2-way = free; x float4 broadcast
    if (t < NND * PC) {
        int pp = t / NND, d = t - pp * NND;
        if (pp < npp) {
            const float*  Ad = Am + d * NND;
            const float4* xr = (const float4*)xs + pp * NND;
            float4 acc = make_float4(0.f, 0.f, 0.f, 0.f);
            #pragma unroll 3
            for (int s = 0; s < NND; s++) {
                float a = Ad[s]; float4 xv = xr[s];
                acc.x += a * xv.x; acc.y += a * xv.y;
                acc.z += a * xv.z; acc.w += a * xv.w;
            }
            ((float4*)ag)[pp * NND + d] = acc;
        }
    }
    __syncthreads();

    // ---- gates + attention-weighted accumulate ----
    int e = t & 31, r = t >> 5;
    float wuz[4], wuh[4];
    #pragma unroll
    for (int f = 0; f < 4; f++) {
        wuz[f] = wu[f * EMB + e];
        wuh[f] = wu[128 + f * EMB + e];
    }
    float bez = beff[e], beh = beff[32 + e];

    float hacc[7] = {0, 0, 0, 0, 0, 0, 0};
    for (int pp = 0; pp < npp; pp++) {
        float p = pr[pp];
        #pragma unroll
        for (int k = 0; k < 7; k++) {
            int d = r + 8 * k;
            if (d < NND) {
                float4 agv = ((const float4*)ag)[pp * NND + d];
                float az = bez + agv.x * wuz[0] + agv.y * wuz[1] + agv.z * wuz[2] + agv.w * wuz[3];
                float ah = beh + agv.x * wuh[0] + agv.y * wuh[1] + agv.z * wuh[2] + agv.w * wuh[3];
                float Z  = 1.0f / (1.0f + __expf(-az));
                float Ht = 2.0f / (1.0f + __expf(-2.0f * ah)) - 1.0f;
                hacc[k] += p * (1.0f - Z) * Ht;
            }
        }
    }
    // disjoint slab write: [b][c][d*EMB+e] — no atomics, covers all 1632 slots
    float* dst = &slab[((size_t)b * NCH + c) * NE];
    #pragma unroll
    for (int k = 0; k < 7; k++) {
        int d = r + 8 * k;
        if (d < NND) dst[d * EMB + e] = hacc[k];
    }
}

// grid(BD). Sum 28 slabs -> relu -> lin1 -> relu -> rank-1 collapsed
// lin2/lin3 -> sigmoid.
__global__ __launch_bounds__(256) void head_kernel(
    const float* __restrict__ slab, const float* __restrict__ W1,
    const float* __restrict__ b1, const float* __restrict__ w2,
    const float* __restrict__ b2, const float* __restrict__ w3,
    const float* __restrict__ b3, float* __restrict__ out)
{
    __shared__ __align__(16) float hs[NE];
    __shared__ float W1s[EMB * EMB];
    __shared__ float b1s[EMB], w2s[EMB];
    __shared__ float w3s[NND];
    __shared__ float wsum[4];
    int t = threadIdx.x, b = blockIdx.x;

    // reduce the 28 partial slabs for this b (float4, coalesced per slab)
    const float4* sl = (const float4*)(slab + (size_t)b * NCH * NE);
    for (int i = t; i < NE / 4; i += 256) {
        float4 a = sl[i];
        #pragma unroll 4
        for (int c2 = 1; c2 < NCH; c2++) {
            float4 v = sl[c2 * (NE / 4) + i];
            a.x += v.x; a.y += v.y; a.z += v.z; a.w += v.w;
        }
        ((float4*)hs)[i] = make_float4(fmaxf(a.x, 0.f), fmaxf(a.y, 0.f),
                                       fmaxf(a.z, 0.f), fmaxf(a.w, 0.f));
    }
    for (int i = t; i < EMB * EMB; i += 256) W1s[i] = W1[i];
    if (t < EMB) { b1s[t] = b1[t]; w2s[t] = w2[t]; }
    if (t < NND) w3s[t] = w3[t];
    __syncthreads();

    float acc = 0.0f;
    for (int i = t; i < NE; i += 256) {
        int d = i >> 5, e = i & 31;
        float a = b1s[e];
        const float* hr = &hs[d * EMB];
        #pragma unroll
        for (int k = 0; k < EMB; k++) a += hr[k] * W1s[k * EMB + e];
        a = fmaxf(a, 0.0f);
        acc += w3s[d] * w2s[e] * a;
    }
    #pragma unroll
    for (int off = 32; off > 0; off >>= 1) acc += __shfl_down(acc, off);
    if ((t & 63) == 0) wsum[t >> 6] = acc;
    __syncthreads();
    if (t == 0) {
        float s = wsum[0] + wsum[1] + wsum[2] + wsum[3];
        float s3 = 0.0f;
        for (int d = 0; d < NND; d++) s3 += w3s[d];
        float v = s + b2[0] * s3 + b3[0];
        out[b] = 1.0f / (1.0f + __expf(-v));
    }
}

extern "C" void kernel_launch(void* const* d_in, const int* in_sizes, int n_in,
                              void* d_out, int out_size, void* d_ws, size_t ws_size,
                              hipStream_t stream) {
    const float* x         = (const float*)d_in[0];
    const int*   ei        = (const int*)d_in[1];
    const float* conv_z_w  = (const float*)d_in[2];
    const float* conv_z_b  = (const float*)d_in[3];
    const float* conv_h_w  = (const float*)d_in[6];
    const float* conv_h_b  = (const float*)d_in[7];
    const float* lin_z_w   = (const float*)d_in[8];
    const float* lin_z_b   = (const float*)d_in[9];
    const float* lin_h_w   = (const float*)d_in[12];
    const float* lin_h_b   = (const float*)d_in[13];
    const float* attention = (const float*)d_in[14];
    const float* lin1_w    = (const float*)d_in[15];
    const float* lin1_b    = (const float*)d_in[16];
    const float* lin2_w    = (const float*)d_in[17];
    const float* lin2_b    = (const float*)d_in[18];
    const float* lin3_w    = (const float*)d_in[19];
    const float* lin3_b    = (const float*)d_in[20];

    float* slab = (float*)d_ws + WS_SLAB;

    hipLaunchKernelGGL(main_kernel, dim3(NCH, BD), dim3(256), 0, stream,
                       x, ei, attention, conv_z_w, conv_z_b, conv_h_w, conv_h_b,
                       lin_z_w, lin_z_b, lin_h_w, lin_h_b, slab);
    hipLaunchKernelGGL(head_kernel, dim3(BD), dim3(256), 0, stream,
                       slab, lin1_w, lin1_b, lin2_w, lin2_b, lin3_w, lin3_b,
                       (float*)d_out);
}